// Round 1
// baseline (7384.486 us; speedup 1.0000x reference)
//
#include <hip/hip_runtime.h>
#include <math.h>

#define LSEQ 256
#define HID 256
#define H2 512
#define H3 768
#define H8 2048

typedef __attribute__((ext_vector_type(8))) short short8;
typedef __attribute__((ext_vector_type(4))) float floatx4;
typedef __attribute__((ext_vector_type(2))) float fx2;

__device__ __forceinline__ float sigmoidf_(float x) { return 1.f / (1.f + __expf(-x)); }
__device__ __forceinline__ unsigned short f2bf(float f) {
    unsigned int u = __float_as_uint(f);
    u = (u + 0x7FFFu + ((u >> 16) & 1u)) >> 16;
    return (unsigned short)u;
}
__device__ __forceinline__ float bf2f(unsigned short h) {
    return __uint_as_float(((unsigned int)h) << 16);
}
__device__ __forceinline__ float fsig(float x) {
    return __builtin_amdgcn_rcpf(1.f + __expf(-x));
}
__device__ __forceinline__ float ftanh(float x) {
    // 2*sigmoid(2x)-1; saturates correctly for large |x| (rcp(inf)=0 -> -1)
    return __builtin_fmaf(2.f, __builtin_amdgcn_rcpf(1.f + __expf(-2.f * x)), -1.f);
}

// ---------------- embed ----------------
__global__ void embed_kernel(const int* __restrict__ question,
                             const int* __restrict__ article,
                             const float* __restrict__ emb,
                             float* __restrict__ xemb) {
    int gid = blockIdx.x * 256 + threadIdx.x;   // 128*256*256
    int d = gid & 255;
    int rl = gid >> 8;
    int l = rl & 255;
    int stream = rl >> 8;
    int id;
    if (stream < 64) {
        int b = stream >> 3, o = (stream & 7) >> 1;
        id = question[(b * 4 + o) * 256 + l];
    } else {
        id = article[(stream - 64) * 256 + l];
    }
    xemb[(size_t)gid] = emb[(size_t)id * 256 + d];
}

// ---------------- MFMA bf16 GEMM ----------------
__global__ __launch_bounds__(256)
void gemm_mfma_bf16(const float* __restrict__ A, const float* __restrict__ B,
                    const float* __restrict__ bias, unsigned short* __restrict__ C,
                    int M, int N, int K) {
    __shared__ unsigned short At[128][40];
    __shared__ unsigned short Bt[128][40];
    int tid = threadIdx.x;
    int m0 = blockIdx.x * 128, n0 = blockIdx.y * 128;
    int l = tid & 63, w = tid >> 6;
    int wm = (w & 1) * 64, wn = (w >> 1) * 64;
    int lr = l & 15, koff = (l >> 4) * 8;
    int srow = tid >> 1, scol = (tid & 1) * 16;
    floatx4 acc[4][4];
#pragma unroll
    for (int i = 0; i < 4; i++)
#pragma unroll
        for (int j = 0; j < 4; j++) acc[i][j] = (floatx4){0.f, 0.f, 0.f, 0.f};
    for (int k0 = 0; k0 < K; k0 += 32) {
        const float* ap = A + (size_t)(m0 + srow) * K + k0 + scol;
        const float* bp = B + (size_t)(n0 + srow) * K + k0 + scol;
        float av[16], bv[16];
        *(float4*)&av[0]  = *(const float4*)(ap);
        *(float4*)&av[4]  = *(const float4*)(ap + 4);
        *(float4*)&av[8]  = *(const float4*)(ap + 8);
        *(float4*)&av[12] = *(const float4*)(ap + 12);
        *(float4*)&bv[0]  = *(const float4*)(bp);
        *(float4*)&bv[4]  = *(const float4*)(bp + 4);
        *(float4*)&bv[8]  = *(const float4*)(bp + 8);
        *(float4*)&bv[12] = *(const float4*)(bp + 12);
        unsigned int aw[8], bw[8];
#pragma unroll
        for (int i = 0; i < 8; i++) {
            aw[i] = (unsigned int)f2bf(av[2 * i]) | ((unsigned int)f2bf(av[2 * i + 1]) << 16);
            bw[i] = (unsigned int)f2bf(bv[2 * i]) | ((unsigned int)f2bf(bv[2 * i + 1]) << 16);
        }
        __syncthreads();
        *(uint4*)&At[srow][scol]     = *(uint4*)&aw[0];
        *(uint4*)&At[srow][scol + 8] = *(uint4*)&aw[4];
        *(uint4*)&Bt[srow][scol]     = *(uint4*)&bw[0];
        *(uint4*)&Bt[srow][scol + 8] = *(uint4*)&bw[4];
        __syncthreads();
        short8 af[4], bf[4];
#pragma unroll
        for (int i = 0; i < 4; i++) {
            af[i] = *(const short8*)&At[wm + i * 16 + lr][koff];
            bf[i] = *(const short8*)&Bt[wn + i * 16 + lr][koff];
        }
#pragma unroll
        for (int i = 0; i < 4; i++)
#pragma unroll
            for (int j = 0; j < 4; j++)
                acc[i][j] = __builtin_amdgcn_mfma_f32_16x16x32_bf16(af[i], bf[j], acc[i][j], 0, 0, 0);
    }
    int quad = l >> 4;
#pragma unroll
    for (int i = 0; i < 4; i++) {
#pragma unroll
        for (int j = 0; j < 4; j++) {
            int n = n0 + wn + j * 16 + lr;
            float bs = bias[n];
#pragma unroll
            for (int r = 0; r < 4; r++) {
                int m = m0 + wm + i * 16 + quad * 4 + r;
                C[(size_t)m * N + n] = f2bf(acc[i][j][r] + bs);
            }
        }
    }
}

// ---------------- whh pack to bf16 [d][768][256] row-major ----------------
__global__ void pack_whh_bf(const float* __restrict__ whh, unsigned short* __restrict__ wq) {
    int i = blockIdx.x * 256 + threadIdx.x;   // 2*768*256 = 393216
    wq[i] = f2bf(whh[i]);
}

// ---------------- GRU scan via MFMA ----------------
// 16 streams per block (one dir), 1024 threads = 16 waves.
// Per step: preact[16s][768n] = h[16s][256k] @ whh^T via mfma_f32_16x16x32_bf16.
// Fragment lane maps copied from gemm_mfma_bf16 (A: row=l&15, k=(l>>4)*8+j;
// B: n=l&15, same k; C: col=l&15, row=(l>>4)*4+r).
// Weights streamed from L2 (384KB/dir, resident); gi prefetched 1 step ahead
// into 12 regs; h kept in LDS bf16 [16][264] (528B rows -> 2-way bank, free).
__global__ __launch_bounds__(1024)
void gru_scan_mfma(const unsigned short* __restrict__ gi_f,
                   const unsigned short* __restrict__ gi_b,
                   const unsigned short* __restrict__ whh_bf,
                   const float* __restrict__ bhh,
                   float* __restrict__ out) {
    int blk = blockIdx.x;
    int d = blk & 1, grp = blk >> 1;
    const unsigned short* gi_blk = (d ? gi_b : gi_f) + (size_t)grp * 16 * LSEQ * H3;
    const unsigned short* wb = whh_bf + (size_t)d * H3 * HID;

    __shared__ __align__(16) unsigned short h_lds[16][264];  // bf16, padded rows
    __shared__ float preact[16 * 768];                       // [s][n] fp32

    int tid = threadIdx.x;
    int lane = tid & 63, wave = tid >> 6;
    int lr = lane & 15, kq = lane >> 4;

    // MFMA-role: wave owns N-tiles {wave*3 + 0,1,2} -> cols wave*48 + {0,16,32} + lr
    const unsigned short* wp0 = wb + (size_t)(wave * 48 + lr) * HID + kq * 8;
    const unsigned short* wp1 = wp0 + 16 * HID;
    const unsigned short* wp2 = wp0 + 32 * HID;

    // gate-role: thread owns (h = tid&255, streams sg*4..sg*4+3)
    int h = tid & 255, sg = tid >> 8;
    float bh_r = bhh[d * H3 + h];
    float bh_z = bhh[d * H3 + 256 + h];
    float bh_n = bhh[d * H3 + 512 + h];
    float hold[4] = {0.f, 0.f, 0.f, 0.f};

    for (int i = tid; i < 16 * 264; i += 1024) ((unsigned short*)h_lds)[i] = 0;

    // prologue: gi for first timestep into regs
    unsigned short pfC[12];
    {
        int t0 = d ? (LSEQ - 1) : 0;
#pragma unroll
        for (int rr = 0; rr < 4; rr++) {
            const unsigned short* gp = gi_blk + ((size_t)(sg * 4 + rr) * LSEQ + t0) * H3 + h;
            pfC[rr * 3 + 0] = gp[0];
            pfC[rr * 3 + 1] = gp[256];
            pfC[rr * 3 + 2] = gp[512];
        }
    }
    __syncthreads();

    for (int step = 0; step < LSEQ; ++step) {
        int t = d ? (LSEQ - 1 - step) : step;
        // prefetch next step's gi (hidden under MFMA phase)
        unsigned short pfN[12];
        if (step + 1 < LSEQ) {
            int t2 = d ? (t - 1) : (t + 1);
#pragma unroll
            for (int rr = 0; rr < 4; rr++) {
                const unsigned short* gp = gi_blk + ((size_t)(sg * 4 + rr) * LSEQ + t2) * H3 + h;
                pfN[rr * 3 + 0] = gp[0];
                pfN[rr * 3 + 1] = gp[256];
                pfN[rr * 3 + 2] = gp[512];
            }
        }
        // ---- MFMA phase: preact = h @ whh^T ----
        floatx4 a0 = {0.f, 0.f, 0.f, 0.f};
        floatx4 a1 = {0.f, 0.f, 0.f, 0.f};
        floatx4 a2 = {0.f, 0.f, 0.f, 0.f};
#pragma unroll 2
        for (int kt = 0; kt < 8; kt++) {
            short8 av = *(const short8*)&h_lds[lr][kt * 32 + kq * 8];
            short8 b0 = *(const short8*)(wp0 + kt * 32);
            short8 b1 = *(const short8*)(wp1 + kt * 32);
            short8 b2 = *(const short8*)(wp2 + kt * 32);
            a0 = __builtin_amdgcn_mfma_f32_16x16x32_bf16(av, b0, a0, 0, 0, 0);
            a1 = __builtin_amdgcn_mfma_f32_16x16x32_bf16(av, b1, a1, 0, 0, 0);
            a2 = __builtin_amdgcn_mfma_f32_16x16x32_bf16(av, b2, a2, 0, 0, 0);
        }
        int c0 = wave * 48 + lr;
#pragma unroll
        for (int rr = 0; rr < 4; rr++) {
            preact[(kq * 4 + rr) * 768 + c0]      = a0[rr];
            preact[(kq * 4 + rr) * 768 + c0 + 16] = a1[rr];
            preact[(kq * 4 + rr) * 768 + c0 + 32] = a2[rr];
        }
        __syncthreads();
        // ---- gate phase: 4 GRU cells per thread ----
#pragma unroll
        for (int rr = 0; rr < 4; rr++) {
            int s = sg * 4 + rr;
            float pr = preact[s * 768 + h];
            float pz = preact[s * 768 + 256 + h];
            float pn = preact[s * 768 + 512 + h];
            float xr = bf2f(pfC[rr * 3 + 0]);
            float xz = bf2f(pfC[rr * 3 + 1]);
            float xn = bf2f(pfC[rr * 3 + 2]);
            float rg = fsig(xr + pr + bh_r);
            float zg = fsig(xz + pz + bh_z);
            float ng = ftanh(xn + rg * (pn + bh_n));
            float hnew = (1.f - zg) * ng + zg * hold[rr];
            hold[rr] = hnew;
            h_lds[s][h] = f2bf(hnew);
            out[((size_t)(grp * 16 + s) * LSEQ + t) * H2 + d * HID + h] = hnew;
        }
        if (step + 1 < LSEQ) {
#pragma unroll
            for (int i = 0; i < 12; i++) pfC[i] = pfN[i];
        }
        __syncthreads();
    }
}

// ---------------- bidaf helpers (fp32, unchanged) ----------------
__global__ void cwqw_kernel(const float* __restrict__ c, const float* __restrict__ q,
                            const float* __restrict__ w,
                            float* __restrict__ cw, float* __restrict__ qw) {
    int row = blockIdx.x;
    int lane = threadIdx.x;
    const float* src; const float* wv; float* dst; int r;
    if (row < 16384) { src = c; wv = w; dst = cw; r = row; }
    else { src = q; wv = w + 512; dst = qw; r = row - 16384; }
    const float* p = src + (size_t)r * H2;
    float acc = 0.f;
    for (int j = lane; j < H2; j += 64) acc += p[j] * wv[j];
    for (int off = 32; off; off >>= 1) acc += __shfl_down(acc, off);
    if (lane == 0) dst[r] = acc;
}

__global__ __launch_bounds__(256)
void smat_kernel(const float* __restrict__ c, const float* __restrict__ q,
                 const float* __restrict__ w2, const float* __restrict__ bvec,
                 const float* __restrict__ cw, const float* __restrict__ qw,
                 float* __restrict__ smat) {
    int b = blockIdx.z;
    int m0 = blockIdx.x * 64, n0 = blockIdx.y * 64;
    const float* A = c + (size_t)b * LSEQ * H2;
    const float* B = q + (size_t)b * LSEQ * H2;
    __shared__ float As[16][64];
    __shared__ float Bs[16][64];
    int tid = threadIdx.x;
    int lr = tid >> 2, lc = (tid & 3) * 4;
    int tm = (tid >> 4) * 4, tn = (tid & 15) * 4;
    float acc[4][4];
#pragma unroll
    for (int i = 0; i < 4; i++)
#pragma unroll
        for (int j = 0; j < 4; j++) acc[i][j] = 0.f;
    for (int k0 = 0; k0 < H2; k0 += 16) {
        float4 av = *(const float4*)(A + (size_t)(m0 + lr) * H2 + k0 + lc);
        float4 wv = *(const float4*)(w2 + k0 + lc);
        As[lc + 0][lr] = av.x * wv.x; As[lc + 1][lr] = av.y * wv.y;
        As[lc + 2][lr] = av.z * wv.z; As[lc + 3][lr] = av.w * wv.w;
        float4 bv = *(const float4*)(B + (size_t)(n0 + lr) * H2 + k0 + lc);
        Bs[lc + 0][lr] = bv.x; Bs[lc + 1][lr] = bv.y; Bs[lc + 2][lr] = bv.z; Bs[lc + 3][lr] = bv.w;
        __syncthreads();
#pragma unroll
        for (int kk = 0; kk < 16; kk++) {
            float4 a0 = *(const float4*)&As[kk][tm];
            float4 b0 = *(const float4*)&Bs[kk][tn];
            float a[4] = {a0.x, a0.y, a0.z, a0.w};
            float bb4[4] = {b0.x, b0.y, b0.z, b0.w};
#pragma unroll
            for (int i = 0; i < 4; i++)
#pragma unroll
                for (int j = 0; j < 4; j++) acc[i][j] += a[i] * bb4[j];
        }
        __syncthreads();
    }
    float bsum = bvec[0] + bvec[1] + bvec[2];
#pragma unroll
    for (int i = 0; i < 4; i++) {
        int m = m0 + tm + i;
        float cwv = cw[b * LSEQ + m];
        float4 o;
        o.x = acc[i][0] + cwv + qw[b * LSEQ + n0 + tn + 0] + bsum;
        o.y = acc[i][1] + cwv + qw[b * LSEQ + n0 + tn + 1] + bsum;
        o.z = acc[i][2] + cwv + qw[b * LSEQ + n0 + tn + 2] + bsum;
        o.w = acc[i][3] + cwv + qw[b * LSEQ + n0 + tn + 3] + bsum;
        *(float4*)(smat + ((size_t)b * LSEQ + m) * LSEQ + n0 + tn) = o;
    }
}

__global__ void softmax_kernel(float* __restrict__ smat, float* __restrict__ rowmax) {
    int row = blockIdx.x;
    int lane = threadIdx.x;
    float* p = smat + (size_t)row * LSEQ;
    float v[4];
    float mx = -1e30f;
#pragma unroll
    for (int j = 0; j < 4; j++) { v[j] = p[lane + j * 64]; mx = fmaxf(mx, v[j]); }
    for (int off = 32; off; off >>= 1) mx = fmaxf(mx, __shfl_down(mx, off));
    mx = __shfl(mx, 0);
    float sum = 0.f;
#pragma unroll
    for (int j = 0; j < 4; j++) { v[j] = __expf(v[j] - mx); sum += v[j]; }
    for (int off = 32; off; off >>= 1) sum += __shfl_down(sum, off);
    sum = __shfl(sum, 0);
    float inv = 1.f / sum;
#pragma unroll
    for (int j = 0; j < 4; j++) p[lane + j * 64] = v[j] * inv;
    if (lane == 0) rowmax[row] = mx;
}

__global__ void bb_kernel(const float* __restrict__ rowmax, float* __restrict__ bb) {
    int b = blockIdx.x; int t = threadIdx.x;
    __shared__ float red[256];
    float v = rowmax[b * LSEQ + t];
    red[t] = v; __syncthreads();
    for (int s = 128; s; s >>= 1) { if (t < s) red[t] = fmaxf(red[t], red[t + s]); __syncthreads(); }
    float mx = red[0]; __syncthreads();
    float e = __expf(v - mx);
    red[t] = e; __syncthreads();
    for (int s = 128; s; s >>= 1) { if (t < s) red[t] += red[t + s]; __syncthreads(); }
    bb[b * LSEQ + t] = e / red[0];
}

__global__ void q2c_kernel(const float* __restrict__ bb, const float* __restrict__ c,
                           float* __restrict__ q2c) {
    int b = blockIdx.x; int t = threadIdx.x;
    float a0 = 0.f, a1 = 0.f;
    for (int i = 0; i < LSEQ; i++) {
        float w = bb[b * LSEQ + i];
        const float* row = c + ((size_t)b * LSEQ + i) * H2;
        a0 += w * row[t];
        a1 += w * row[t + 256];
    }
    q2c[b * H2 + t] = a0;
    q2c[b * H2 + t + 256] = a1;
}

__global__ __launch_bounds__(256)
void c2q_fixup(const float* __restrict__ amat, const float* __restrict__ q,
               const float* __restrict__ c, float* __restrict__ att, int add) {
    int b = blockIdx.z;
    int m0 = blockIdx.x * 64, n0 = blockIdx.y * 64;
    const float* A = amat + (size_t)b * LSEQ * LSEQ;
    const float* B = q + (size_t)b * LSEQ * H2;
    __shared__ float As[16][64];
    __shared__ float Bs[16][64];
    int tid = threadIdx.x;
    int lr = tid >> 2, lc = (tid & 3) * 4;
    int br = tid >> 4, bc = (tid & 15) * 4;
    int tm = (tid >> 4) * 4, tn = (tid & 15) * 4;
    float acc[4][4];
#pragma unroll
    for (int i = 0; i < 4; i++)
#pragma unroll
        for (int j = 0; j < 4; j++) acc[i][j] = 0.f;
    for (int k0 = 0; k0 < LSEQ; k0 += 16) {
        float4 av = *(const float4*)(A + (size_t)(m0 + lr) * LSEQ + k0 + lc);
        As[lc + 0][lr] = av.x; As[lc + 1][lr] = av.y; As[lc + 2][lr] = av.z; As[lc + 3][lr] = av.w;
        float4 bv = *(const float4*)(B + (size_t)(k0 + br) * H2 + n0 + bc);
        *(float4*)&Bs[br][bc] = bv;
        __syncthreads();
#pragma unroll
        for (int kk = 0; kk < 16; kk++) {
            float4 a0 = *(const float4*)&As[kk][tm];
            float4 b0 = *(const float4*)&Bs[kk][tn];
            float a[4] = {a0.x, a0.y, a0.z, a0.w};
            float bb4[4] = {b0.x, b0.y, b0.z, b0.w};
#pragma unroll
            for (int i = 0; i < 4; i++)
#pragma unroll
                for (int j = 0; j < 4; j++) acc[i][j] += a[i] * bb4[j];
        }
        __syncthreads();
    }
#pragma unroll
    for (int i = 0; i < 4; i++) {
        int row = b * LSEQ + m0 + tm + i;
        float4 cv = *(const float4*)(c + (size_t)row * H2 + n0 + tn);
        float4 v1, v2;
        v1.x = fmaxf(acc[i][0], 0.f); v1.y = fmaxf(acc[i][1], 0.f);
        v1.z = fmaxf(acc[i][2], 0.f); v1.w = fmaxf(acc[i][3], 0.f);
        v2.x = fmaxf(cv.x * acc[i][0], 0.f); v2.y = fmaxf(cv.y * acc[i][1], 0.f);
        v2.z = fmaxf(cv.z * acc[i][2], 0.f); v2.w = fmaxf(cv.w * acc[i][3], 0.f);
        float* p1 = att + (size_t)row * H8 + 512 + n0 + tn;
        float* p2 = att + (size_t)row * H8 + 1024 + n0 + tn;
        if (add) {
            float4 o1 = *(float4*)p1, o2 = *(float4*)p2;
            o1.x += v1.x; o1.y += v1.y; o1.z += v1.z; o1.w += v1.w;
            o2.x += v2.x; o2.y += v2.y; o2.z += v2.z; o2.w += v2.w;
            *(float4*)p1 = o1; *(float4*)p2 = o2;
        } else {
            *(float4*)p1 = v1; *(float4*)p2 = v2;
        }
    }
}

__global__ void fixup03(const float* __restrict__ c, const float* __restrict__ q2c,
                        float* __restrict__ att, int add) {
    int row = blockIdx.x;
    int t = threadIdx.x;
    int b = row >> 8;
    float* o = att + (size_t)row * H8;
#pragma unroll
    for (int rep = 0; rep < 2; rep++) {
        int d = t + rep * 256;
        float cv = c[(size_t)row * H2 + d];
        float qv = q2c[b * H2 + d];
        float v0 = fmaxf(cv, 0.f);
        float v3 = fmaxf(cv * qv, 0.f);
        if (add) { o[d] += v0; o[d + 1536] += v3; }
        else     { o[d]  = v0; o[d + 1536]  = v3; }
    }
}

// ---------------- final rank reduce ----------------
__global__ void reduce1_kernel(const float* __restrict__ s, const float* __restrict__ rw,
                               float* __restrict__ part) {
    int bo = blockIdx.x;
    int p = blockIdx.y;
    int t = threadIdx.x;
    const float* s0 = s + (size_t)(2 * bo) * 524288;
    const float* s1 = s0 + 524288;
    size_t base = (size_t)p * 65536;
    float acc = 0.f;
    for (int j = t; j < 65536; j += 256) {
        size_t m = base + j;
        acc += rw[m] * fmaxf(s0[m], s1[m]);
    }
    __shared__ float red[256];
    red[t] = acc; __syncthreads();
    for (int ss = 128; ss; ss >>= 1) { if (t < ss) red[t] += red[t + ss]; __syncthreads(); }
    if (t == 0) part[bo * 8 + p] = red[0];
}

__global__ void reduce2_kernel(const float* __restrict__ part, const float* __restrict__ rb,
                               float* __restrict__ out) {
    int t = threadIdx.x;
    float a = rb[0];
    for (int p = 0; p < 8; p++) a += part[t * 8 + p];
    out[t] = a;
}

extern "C" void kernel_launch(void* const* d_in, const int* in_sizes, int n_in,
                              void* d_out, int out_size, void* d_ws, size_t ws_size,
                              hipStream_t stream) {
    const int* question = (const int*)d_in[0];
    const int* article  = (const int*)d_in[1];
    const float* emb    = (const float*)d_in[2];
    const float* g1_wih = (const float*)d_in[3];
    const float* g1_whh = (const float*)d_in[4];
    const float* g1_bih = (const float*)d_in[5];
    const float* g1_bhh = (const float*)d_in[6];
    const float* g2_wih = (const float*)d_in[7];
    const float* g2_whh = (const float*)d_in[8];
    const float* g2_bih = (const float*)d_in[9];
    const float* g2_bhh = (const float*)d_in[10];
    const float* b1_w   = (const float*)d_in[11];
    const float* b1_b   = (const float*)d_in[12];
    const float* b2_w   = (const float*)d_in[13];
    const float* b2_b   = (const float*)d_in[14];
    const float* rank_w = (const float*)d_in[15];
    const float* rank_b = (const float*)d_in[16];
    float* ws = (float*)d_ws;
    float* out = (float*)d_out;

    // ---- workspace layout (fp32 slots) — peak 224 MiB (proven budget) ----
    float*          HBUF  = ws;
    float*          ATT   = ws + 16777216;
    float*          XEMB  = ws + 16777216;
    unsigned short* GI1B  = (unsigned short*)(ws + 25165824);  // 2 dirs x 32768 x 768 bf16
    unsigned short* WPK1  = (unsigned short*)(ws + 50331648);  // 393216 bf16 (768KB)
    float*          SMAT1 = ws + 50331648;
    float*          S1    = ws + 54525952;
    unsigned short* GI2B  = (unsigned short*)ws;               // 2 dirs x 16384 x 768 bf16
    unsigned short* WPK2  = (unsigned short*)(ws + 12582912);
    float*          AX2   = ws + 50331648;
    float*          SMAT2 = ws;
    float*          S2    = ws + 4194304;

    // 1. embed + pack whh1 (bf16 row-major [d][768][256])
    embed_kernel<<<32768, 256, 0, stream>>>(question, article, emb, XEMB);
    pack_whh_bf<<<1536, 256, 0, stream>>>(g1_whh, WPK1);

    // 2. GRU1 input gates via MFMA: per dir, M=32768 N=768 K=256
    for (int d = 0; d < 2; d++) {
        gemm_mfma_bf16<<<dim3(256, 6), 256, 0, stream>>>(
            XEMB, g1_wih + (size_t)d * 196608, g1_bih + d * 768,
            GI1B + (size_t)d * 32768 * 768, 32768, 768, 256);
    }
    // 3. GRU1 scan via MFMA: 16 blocks (2 dirs x 8 groups of 16 streams) x 1024 thr
    gru_scan_mfma<<<16, 1024, 0, stream>>>(GI1B, GI1B + (size_t)32768 * 768, WPK1, g1_bhh, HBUF);

    float* QH = HBUF;
    float* AH = HBUF + (size_t)64 * 256 * 512;

    // 4. BiDAF1: c=QH, q=AH -> ATT (set)
    {
        float* CW = S1, *QW = S1 + 16384, *RM = S1 + 32768, *BBv = S1 + 49152, *Q2C = S1 + 65536;
        cwqw_kernel<<<32768, 64, 0, stream>>>(QH, AH, b1_w, CW, QW);
        smat_kernel<<<dim3(4, 4, 64), 256, 0, stream>>>(QH, AH, b1_w + 1024, b1_b, CW, QW, SMAT1);
        softmax_kernel<<<16384, 64, 0, stream>>>(SMAT1, RM);
        bb_kernel<<<64, 256, 0, stream>>>(RM, BBv);
        q2c_kernel<<<64, 256, 0, stream>>>(BBv, QH, Q2C);
        fixup03<<<16384, 256, 0, stream>>>(QH, Q2C, ATT, 0);
        c2q_fixup<<<dim3(4, 8, 64), 256, 0, stream>>>(SMAT1, AH, QH, ATT, 0);
    }

    // pack whh2 (HBUF dead, region free)
    pack_whh_bf<<<1536, 256, 0, stream>>>(g2_whh, WPK2);

    // 5. GRU2 input gates via MFMA: per dir, M=16384 N=768 K=2048
    for (int d = 0; d < 2; d++) {
        gemm_mfma_bf16<<<dim3(128, 6), 256, 0, stream>>>(
            ATT, g2_wih + (size_t)d * 1572864, g2_bih + d * 768,
            GI2B + (size_t)d * 16384 * 768, 16384, 768, 2048);
    }
    // 6. GRU2 scan via MFMA: 8 blocks (2 dirs x 4 groups of 16 streams)
    gru_scan_mfma<<<8, 1024, 0, stream>>>(GI2B, GI2B + (size_t)16384 * 768, WPK2, g2_bhh, AX2);

    // 7. BiDAF2: c=q=AX2 -> ATT (accumulate)
    {
        float* CW = S2, *QW = S2 + 16384, *RM = S2 + 32768, *BBv = S2 + 49152, *Q2C = S2 + 65536;
        cwqw_kernel<<<32768, 64, 0, stream>>>(AX2, AX2, b2_w, CW, QW);
        smat_kernel<<<dim3(4, 4, 64), 256, 0, stream>>>(AX2, AX2, b2_w + 1024, b2_b, CW, QW, SMAT2);
        softmax_kernel<<<16384, 64, 0, stream>>>(SMAT2, RM);
        bb_kernel<<<64, 256, 0, stream>>>(RM, BBv);
        q2c_kernel<<<64, 256, 0, stream>>>(BBv, AX2, Q2C);
        fixup03<<<16384, 256, 0, stream>>>(AX2, Q2C, ATT, 1);
        c2q_fixup<<<dim3(4, 8, 64), 256, 0, stream>>>(SMAT2, AX2, AX2, ATT, 1);
    }

    // 8. rank reduce
    float* PART = S2 + 98304;
    reduce1_kernel<<<dim3(32, 8), 256, 0, stream>>>(ATT, rank_w, PART);
    reduce2_kernel<<<1, 32, 0, stream>>>(PART, rank_b, out);
}

// Round 2
// 1632.851 us; speedup vs baseline: 4.5224x; 4.5224x over previous
//
#include <hip/hip_runtime.h>
#include <math.h>

#define LSEQ 256
#define HID 256
#define H2 512
#define H3 768
#define H8 2048

typedef __attribute__((ext_vector_type(8))) short short8;
typedef __attribute__((ext_vector_type(4))) float floatx4;
typedef __attribute__((ext_vector_type(2))) float fx2;

__device__ __forceinline__ float sigmoidf_(float x) { return 1.f / (1.f + __expf(-x)); }
__device__ __forceinline__ unsigned short f2bf(float f) {
    unsigned int u = __float_as_uint(f);
    u = (u + 0x7FFFu + ((u >> 16) & 1u)) >> 16;
    return (unsigned short)u;
}
__device__ __forceinline__ float bf2f(unsigned short h) {
    return __uint_as_float(((unsigned int)h) << 16);
}
__device__ __forceinline__ float fsig(float x) {
    return __builtin_amdgcn_rcpf(1.f + __expf(-x));
}
__device__ __forceinline__ float ftanh(float x) {
    // 2*sigmoid(2x)-1; saturates correctly for large |x| (rcp(inf)=0 -> -1)
    return __builtin_fmaf(2.f, __builtin_amdgcn_rcpf(1.f + __expf(-2.f * x)), -1.f);
}

// ---------------- embed ----------------
__global__ void embed_kernel(const int* __restrict__ question,
                             const int* __restrict__ article,
                             const float* __restrict__ emb,
                             float* __restrict__ xemb) {
    int gid = blockIdx.x * 256 + threadIdx.x;   // 128*256*256
    int d = gid & 255;
    int rl = gid >> 8;
    int l = rl & 255;
    int stream = rl >> 8;
    int id;
    if (stream < 64) {
        int b = stream >> 3, o = (stream & 7) >> 1;
        id = question[(b * 4 + o) * 256 + l];
    } else {
        id = article[(stream - 64) * 256 + l];
    }
    xemb[(size_t)gid] = emb[(size_t)id * 256 + d];
}

// ---------------- MFMA bf16 GEMM ----------------
__global__ __launch_bounds__(256)
void gemm_mfma_bf16(const float* __restrict__ A, const float* __restrict__ B,
                    const float* __restrict__ bias, unsigned short* __restrict__ C,
                    int M, int N, int K) {
    __shared__ unsigned short At[128][40];
    __shared__ unsigned short Bt[128][40];
    int tid = threadIdx.x;
    int m0 = blockIdx.x * 128, n0 = blockIdx.y * 128;
    int l = tid & 63, w = tid >> 6;
    int wm = (w & 1) * 64, wn = (w >> 1) * 64;
    int lr = l & 15, koff = (l >> 4) * 8;
    int srow = tid >> 1, scol = (tid & 1) * 16;
    floatx4 acc[4][4];
#pragma unroll
    for (int i = 0; i < 4; i++)
#pragma unroll
        for (int j = 0; j < 4; j++) acc[i][j] = (floatx4){0.f, 0.f, 0.f, 0.f};
    for (int k0 = 0; k0 < K; k0 += 32) {
        const float* ap = A + (size_t)(m0 + srow) * K + k0 + scol;
        const float* bp = B + (size_t)(n0 + srow) * K + k0 + scol;
        float av[16], bv[16];
        *(float4*)&av[0]  = *(const float4*)(ap);
        *(float4*)&av[4]  = *(const float4*)(ap + 4);
        *(float4*)&av[8]  = *(const float4*)(ap + 8);
        *(float4*)&av[12] = *(const float4*)(ap + 12);
        *(float4*)&bv[0]  = *(const float4*)(bp);
        *(float4*)&bv[4]  = *(const float4*)(bp + 4);
        *(float4*)&bv[8]  = *(const float4*)(bp + 8);
        *(float4*)&bv[12] = *(const float4*)(bp + 12);
        unsigned int aw[8], bw[8];
#pragma unroll
        for (int i = 0; i < 8; i++) {
            aw[i] = (unsigned int)f2bf(av[2 * i]) | ((unsigned int)f2bf(av[2 * i + 1]) << 16);
            bw[i] = (unsigned int)f2bf(bv[2 * i]) | ((unsigned int)f2bf(bv[2 * i + 1]) << 16);
        }
        __syncthreads();
        *(uint4*)&At[srow][scol]     = *(uint4*)&aw[0];
        *(uint4*)&At[srow][scol + 8] = *(uint4*)&aw[4];
        *(uint4*)&Bt[srow][scol]     = *(uint4*)&bw[0];
        *(uint4*)&Bt[srow][scol + 8] = *(uint4*)&bw[4];
        __syncthreads();
        short8 af[4], bf[4];
#pragma unroll
        for (int i = 0; i < 4; i++) {
            af[i] = *(const short8*)&At[wm + i * 16 + lr][koff];
            bf[i] = *(const short8*)&Bt[wn + i * 16 + lr][koff];
        }
#pragma unroll
        for (int i = 0; i < 4; i++)
#pragma unroll
            for (int j = 0; j < 4; j++)
                acc[i][j] = __builtin_amdgcn_mfma_f32_16x16x32_bf16(af[i], bf[j], acc[i][j], 0, 0, 0);
    }
    int quad = l >> 4;
#pragma unroll
    for (int i = 0; i < 4; i++) {
#pragma unroll
        for (int j = 0; j < 4; j++) {
            int n = n0 + wn + j * 16 + lr;
            float bs = bias[n];
#pragma unroll
            for (int r = 0; r < 4; r++) {
                int m = m0 + wm + i * 16 + quad * 4 + r;
                C[(size_t)m * N + n] = f2bf(acc[i][j][r] + bs);
            }
        }
    }
}

// ---------------- whh pack to bf16 [d][768][256] row-major ----------------
__global__ void pack_whh_bf(const float* __restrict__ whh, unsigned short* __restrict__ wq) {
    int i = blockIdx.x * 256 + threadIdx.x;   // 2*768*256 = 393216
    wq[i] = f2bf(whh[i]);
}

// ---------------- GRU scan: 1 stream/block, whh resident in VGPRs ----------------
// 512 threads = 8 waves; wave w owns output cols [96w, 96w+96) as 6 N-tiles.
// Weights: 48 short8 B-fragments per thread (192 VGPR), loaded once.
// A-operand: all lanes broadcast-read the same 16B of h from LDS -> every
// row of A equals h -> every row of D equals the matvec; no masking needed.
// Per step: 48 MFMA/wave + 8 broadcast ds_read_b128 + 6 masked ds_write_b32
// + 2 barriers + 256-thread gate phase. gi prefetched 1 step ahead.
__global__ __launch_bounds__(512, 2)
void gru_scan_rreg(const unsigned short* __restrict__ gi_f,
                   const unsigned short* __restrict__ gi_b,
                   const unsigned short* __restrict__ whh_bf,
                   const float* __restrict__ bhh,
                   float* __restrict__ out) {
    int blk = blockIdx.x;
    int d = blk & 1, s = blk >> 1;
    const unsigned short* gi_blk = (d ? gi_b : gi_f) + (size_t)s * LSEQ * H3;
    const unsigned short* wb = whh_bf + (size_t)d * H3 * HID;

    __shared__ __align__(16) unsigned short h_pack[256];  // h as bf16
    __shared__ float preact[H3];

    int tid = threadIdx.x;
    int lane = tid & 63, wave = tid >> 6;
    int lr = lane & 15, kq = lane >> 4;

    // ---- preload weights into registers (B-fragment layout) ----
    short8 bq[6][8];
#pragma unroll
    for (int nt = 0; nt < 6; nt++) {
        const unsigned short* wp = wb + (size_t)(wave * 96 + nt * 16 + lr) * HID + kq * 8;
#pragma unroll
        for (int kt = 0; kt < 8; kt++)
            bq[nt][kt] = *(const short8*)(wp + kt * 32);
    }

    int t0 = d ? (LSEQ - 1) : 0;
    int tstep = d ? -1 : 1;

    float bh_r = 0.f, bh_z = 0.f, bh_n = 0.f, hold = 0.f;
    unsigned short pfr = 0, pfz = 0, pfn_ = 0;
    if (tid < 256) {
        bh_r = bhh[d * H3 + tid];
        bh_z = bhh[d * H3 + 256 + tid];
        bh_n = bhh[d * H3 + 512 + tid];
        h_pack[tid] = 0;
        const unsigned short* gp = gi_blk + (size_t)t0 * H3 + tid;
        pfr = gp[0]; pfz = gp[256]; pfn_ = gp[512];
    }
    __syncthreads();

    int t = t0;
    for (int step = 0; step < LSEQ; ++step) {
        // prefetch next step's gi (hidden under MFMA phase)
        unsigned short nr = 0, nz = 0, nn = 0;
        if (step + 1 < LSEQ && tid < 256) {
            const unsigned short* gp = gi_blk + (size_t)(t + tstep) * H3 + tid;
            nr = gp[0]; nz = gp[256]; nn = gp[512];
        }
        // ---- MFMA phase: preact[col] = sum_k h[k] * whh[col][k] ----
        floatx4 acc[6];
#pragma unroll
        for (int nt = 0; nt < 6; nt++) acc[nt] = (floatx4){0.f, 0.f, 0.f, 0.f};
#pragma unroll
        for (int kt = 0; kt < 8; kt++) {
            short8 av = *(const short8*)&h_pack[kt * 32 + kq * 8];  // broadcast
#pragma unroll
            for (int nt = 0; nt < 6; nt++)
                acc[nt] = __builtin_amdgcn_mfma_f32_16x16x32_bf16(av, bq[nt][kt], acc[nt], 0, 0, 0);
        }
        if (lane < 16) {
#pragma unroll
            for (int nt = 0; nt < 6; nt++)
                preact[wave * 96 + nt * 16 + lane] = acc[nt][0];
        }
        __syncthreads();
        // ---- gate phase: thread tid<256 owns cell tid ----
        if (tid < 256) {
            float rg = fsig(bf2f(pfr) + preact[tid] + bh_r);
            float zg = fsig(bf2f(pfz) + preact[tid + 256] + bh_z);
            float ng = ftanh(bf2f(pfn_) + rg * (preact[tid + 512] + bh_n));
            float hnew = (1.f - zg) * ng + zg * hold;
            hold = hnew;
            h_pack[tid] = f2bf(hnew);
            out[((size_t)s * LSEQ + t) * H2 + d * HID + tid] = hnew;
            pfr = nr; pfz = nz; pfn_ = nn;
        }
        __syncthreads();
        t += tstep;
    }
}

// ---------------- bidaf helpers (fp32, unchanged) ----------------
__global__ void cwqw_kernel(const float* __restrict__ c, const float* __restrict__ q,
                            const float* __restrict__ w,
                            float* __restrict__ cw, float* __restrict__ qw) {
    int row = blockIdx.x;
    int lane = threadIdx.x;
    const float* src; const float* wv; float* dst; int r;
    if (row < 16384) { src = c; wv = w; dst = cw; r = row; }
    else { src = q; wv = w + 512; dst = qw; r = row - 16384; }
    const float* p = src + (size_t)r * H2;
    float acc = 0.f;
    for (int j = lane; j < H2; j += 64) acc += p[j] * wv[j];
    for (int off = 32; off; off >>= 1) acc += __shfl_down(acc, off);
    if (lane == 0) dst[r] = acc;
}

__global__ __launch_bounds__(256)
void smat_kernel(const float* __restrict__ c, const float* __restrict__ q,
                 const float* __restrict__ w2, const float* __restrict__ bvec,
                 const float* __restrict__ cw, const float* __restrict__ qw,
                 float* __restrict__ smat) {
    int b = blockIdx.z;
    int m0 = blockIdx.x * 64, n0 = blockIdx.y * 64;
    const float* A = c + (size_t)b * LSEQ * H2;
    const float* B = q + (size_t)b * LSEQ * H2;
    __shared__ float As[16][64];
    __shared__ float Bs[16][64];
    int tid = threadIdx.x;
    int lr = tid >> 2, lc = (tid & 3) * 4;
    int tm = (tid >> 4) * 4, tn = (tid & 15) * 4;
    float acc[4][4];
#pragma unroll
    for (int i = 0; i < 4; i++)
#pragma unroll
        for (int j = 0; j < 4; j++) acc[i][j] = 0.f;
    for (int k0 = 0; k0 < H2; k0 += 16) {
        float4 av = *(const float4*)(A + (size_t)(m0 + lr) * H2 + k0 + lc);
        float4 wv = *(const float4*)(w2 + k0 + lc);
        As[lc + 0][lr] = av.x * wv.x; As[lc + 1][lr] = av.y * wv.y;
        As[lc + 2][lr] = av.z * wv.z; As[lc + 3][lr] = av.w * wv.w;
        float4 bv = *(const float4*)(B + (size_t)(n0 + lr) * H2 + k0 + lc);
        Bs[lc + 0][lr] = bv.x; Bs[lc + 1][lr] = bv.y; Bs[lc + 2][lr] = bv.z; Bs[lc + 3][lr] = bv.w;
        __syncthreads();
#pragma unroll
        for (int kk = 0; kk < 16; kk++) {
            float4 a0 = *(const float4*)&As[kk][tm];
            float4 b0 = *(const float4*)&Bs[kk][tn];
            float a[4] = {a0.x, a0.y, a0.z, a0.w};
            float bb4[4] = {b0.x, b0.y, b0.z, b0.w};
#pragma unroll
            for (int i = 0; i < 4; i++)
#pragma unroll
                for (int j = 0; j < 4; j++) acc[i][j] += a[i] * bb4[j];
        }
        __syncthreads();
    }
    float bsum = bvec[0] + bvec[1] + bvec[2];
#pragma unroll
    for (int i = 0; i < 4; i++) {
        int m = m0 + tm + i;
        float cwv = cw[b * LSEQ + m];
        float4 o;
        o.x = acc[i][0] + cwv + qw[b * LSEQ + n0 + tn + 0] + bsum;
        o.y = acc[i][1] + cwv + qw[b * LSEQ + n0 + tn + 1] + bsum;
        o.z = acc[i][2] + cwv + qw[b * LSEQ + n0 + tn + 2] + bsum;
        o.w = acc[i][3] + cwv + qw[b * LSEQ + n0 + tn + 3] + bsum;
        *(float4*)(smat + ((size_t)b * LSEQ + m) * LSEQ + n0 + tn) = o;
    }
}

__global__ void softmax_kernel(float* __restrict__ smat, float* __restrict__ rowmax) {
    int row = blockIdx.x;
    int lane = threadIdx.x;
    float* p = smat + (size_t)row * LSEQ;
    float v[4];
    float mx = -1e30f;
#pragma unroll
    for (int j = 0; j < 4; j++) { v[j] = p[lane + j * 64]; mx = fmaxf(mx, v[j]); }
    for (int off = 32; off; off >>= 1) mx = fmaxf(mx, __shfl_down(mx, off));
    mx = __shfl(mx, 0);
    float sum = 0.f;
#pragma unroll
    for (int j = 0; j < 4; j++) { v[j] = __expf(v[j] - mx); sum += v[j]; }
    for (int off = 32; off; off >>= 1) sum += __shfl_down(sum, off);
    sum = __shfl(sum, 0);
    float inv = 1.f / sum;
#pragma unroll
    for (int j = 0; j < 4; j++) p[lane + j * 64] = v[j] * inv;
    if (lane == 0) rowmax[row] = mx;
}

__global__ void bb_kernel(const float* __restrict__ rowmax, float* __restrict__ bb) {
    int b = blockIdx.x; int t = threadIdx.x;
    __shared__ float red[256];
    float v = rowmax[b * LSEQ + t];
    red[t] = v; __syncthreads();
    for (int s = 128; s; s >>= 1) { if (t < s) red[t] = fmaxf(red[t], red[t + s]); __syncthreads(); }
    float mx = red[0]; __syncthreads();
    float e = __expf(v - mx);
    red[t] = e; __syncthreads();
    for (int s = 128; s; s >>= 1) { if (t < s) red[t] += red[t + s]; __syncthreads(); }
    bb[b * LSEQ + t] = e / red[0];
}

__global__ void q2c_kernel(const float* __restrict__ bb, const float* __restrict__ c,
                           float* __restrict__ q2c) {
    int b = blockIdx.x; int t = threadIdx.x;
    float a0 = 0.f, a1 = 0.f;
    for (int i = 0; i < LSEQ; i++) {
        float w = bb[b * LSEQ + i];
        const float* row = c + ((size_t)b * LSEQ + i) * H2;
        a0 += w * row[t];
        a1 += w * row[t + 256];
    }
    q2c[b * H2 + t] = a0;
    q2c[b * H2 + t + 256] = a1;
}

__global__ __launch_bounds__(256)
void c2q_fixup(const float* __restrict__ amat, const float* __restrict__ q,
               const float* __restrict__ c, float* __restrict__ att, int add) {
    int b = blockIdx.z;
    int m0 = blockIdx.x * 64, n0 = blockIdx.y * 64;
    const float* A = amat + (size_t)b * LSEQ * LSEQ;
    const float* B = q + (size_t)b * LSEQ * H2;
    __shared__ float As[16][64];
    __shared__ float Bs[16][64];
    int tid = threadIdx.x;
    int lr = tid >> 2, lc = (tid & 3) * 4;
    int br = tid >> 4, bc = (tid & 15) * 4;
    int tm = (tid >> 4) * 4, tn = (tid & 15) * 4;
    float acc[4][4];
#pragma unroll
    for (int i = 0; i < 4; i++)
#pragma unroll
        for (int j = 0; j < 4; j++) acc[i][j] = 0.f;
    for (int k0 = 0; k0 < LSEQ; k0 += 16) {
        float4 av = *(const float4*)(A + (size_t)(m0 + lr) * LSEQ + k0 + lc);
        As[lc + 0][lr] = av.x; As[lc + 1][lr] = av.y; As[lc + 2][lr] = av.z; As[lc + 3][lr] = av.w;
        float4 bv = *(const float4*)(B + (size_t)(k0 + br) * H2 + n0 + bc);
        *(float4*)&Bs[br][bc] = bv;
        __syncthreads();
#pragma unroll
        for (int kk = 0; kk < 16; kk++) {
            float4 a0 = *(const float4*)&As[kk][tm];
            float4 b0 = *(const float4*)&Bs[kk][tn];
            float a[4] = {a0.x, a0.y, a0.z, a0.w};
            float bb4[4] = {b0.x, b0.y, b0.z, b0.w};
#pragma unroll
            for (int i = 0; i < 4; i++)
#pragma unroll
                for (int j = 0; j < 4; j++) acc[i][j] += a[i] * bb4[j];
        }
        __syncthreads();
    }
#pragma unroll
    for (int i = 0; i < 4; i++) {
        int row = b * LSEQ + m0 + tm + i;
        float4 cv = *(const float4*)(c + (size_t)row * H2 + n0 + tn);
        float4 v1, v2;
        v1.x = fmaxf(acc[i][0], 0.f); v1.y = fmaxf(acc[i][1], 0.f);
        v1.z = fmaxf(acc[i][2], 0.f); v1.w = fmaxf(acc[i][3], 0.f);
        v2.x = fmaxf(cv.x * acc[i][0], 0.f); v2.y = fmaxf(cv.y * acc[i][1], 0.f);
        v2.z = fmaxf(cv.z * acc[i][2], 0.f); v2.w = fmaxf(cv.w * acc[i][3], 0.f);
        float* p1 = att + (size_t)row * H8 + 512 + n0 + tn;
        float* p2 = att + (size_t)row * H8 + 1024 + n0 + tn;
        if (add) {
            float4 o1 = *(float4*)p1, o2 = *(float4*)p2;
            o1.x += v1.x; o1.y += v1.y; o1.z += v1.z; o1.w += v1.w;
            o2.x += v2.x; o2.y += v2.y; o2.z += v2.z; o2.w += v2.w;
            *(float4*)p1 = o1; *(float4*)p2 = o2;
        } else {
            *(float4*)p1 = v1; *(float4*)p2 = v2;
        }
    }
}

__global__ void fixup03(const float* __restrict__ c, const float* __restrict__ q2c,
                        float* __restrict__ att, int add) {
    int row = blockIdx.x;
    int t = threadIdx.x;
    int b = row >> 8;
    float* o = att + (size_t)row * H8;
#pragma unroll
    for (int rep = 0; rep < 2; rep++) {
        int d = t + rep * 256;
        float cv = c[(size_t)row * H2 + d];
        float qv = q2c[b * H2 + d];
        float v0 = fmaxf(cv, 0.f);
        float v3 = fmaxf(cv * qv, 0.f);
        if (add) { o[d] += v0; o[d + 1536] += v3; }
        else     { o[d]  = v0; o[d + 1536]  = v3; }
    }
}

// ---------------- final rank reduce ----------------
__global__ void reduce1_kernel(const float* __restrict__ s, const float* __restrict__ rw,
                               float* __restrict__ part) {
    int bo = blockIdx.x;
    int p = blockIdx.y;
    int t = threadIdx.x;
    const float* s0 = s + (size_t)(2 * bo) * 524288;
    const float* s1 = s0 + 524288;
    size_t base = (size_t)p * 65536;
    float acc = 0.f;
    for (int j = t; j < 65536; j += 256) {
        size_t m = base + j;
        acc += rw[m] * fmaxf(s0[m], s1[m]);
    }
    __shared__ float red[256];
    red[t] = acc; __syncthreads();
    for (int ss = 128; ss; ss >>= 1) { if (t < ss) red[t] += red[t + ss]; __syncthreads(); }
    if (t == 0) part[bo * 8 + p] = red[0];
}

__global__ void reduce2_kernel(const float* __restrict__ part, const float* __restrict__ rb,
                               float* __restrict__ out) {
    int t = threadIdx.x;
    float a = rb[0];
    for (int p = 0; p < 8; p++) a += part[t * 8 + p];
    out[t] = a;
}

extern "C" void kernel_launch(void* const* d_in, const int* in_sizes, int n_in,
                              void* d_out, int out_size, void* d_ws, size_t ws_size,
                              hipStream_t stream) {
    const int* question = (const int*)d_in[0];
    const int* article  = (const int*)d_in[1];
    const float* emb    = (const float*)d_in[2];
    const float* g1_wih = (const float*)d_in[3];
    const float* g1_whh = (const float*)d_in[4];
    const float* g1_bih = (const float*)d_in[5];
    const float* g1_bhh = (const float*)d_in[6];
    const float* g2_wih = (const float*)d_in[7];
    const float* g2_whh = (const float*)d_in[8];
    const float* g2_bih = (const float*)d_in[9];
    const float* g2_bhh = (const float*)d_in[10];
    const float* b1_w   = (const float*)d_in[11];
    const float* b1_b   = (const float*)d_in[12];
    const float* b2_w   = (const float*)d_in[13];
    const float* b2_b   = (const float*)d_in[14];
    const float* rank_w = (const float*)d_in[15];
    const float* rank_b = (const float*)d_in[16];
    float* ws = (float*)d_ws;
    float* out = (float*)d_out;

    // ---- workspace layout (fp32 slots) — peak 224 MiB (proven budget) ----
    float*          HBUF  = ws;
    float*          ATT   = ws + 16777216;
    float*          XEMB  = ws + 16777216;
    unsigned short* GI1B  = (unsigned short*)(ws + 25165824);  // 2 dirs x 32768 x 768 bf16
    unsigned short* WPK1  = (unsigned short*)(ws + 50331648);  // 393216 bf16 (768KB)
    float*          SMAT1 = ws + 50331648;
    float*          S1    = ws + 54525952;
    unsigned short* GI2B  = (unsigned short*)ws;               // 2 dirs x 16384 x 768 bf16
    unsigned short* WPK2  = (unsigned short*)(ws + 12582912);
    float*          AX2   = ws + 50331648;
    float*          SMAT2 = ws;
    float*          S2    = ws + 4194304;

    // 1. embed + pack whh1 (bf16 row-major [d][768][256])
    embed_kernel<<<32768, 256, 0, stream>>>(question, article, emb, XEMB);
    pack_whh_bf<<<1536, 256, 0, stream>>>(g1_whh, WPK1);

    // 2. GRU1 input gates via MFMA: per dir, M=32768 N=768 K=256
    for (int d = 0; d < 2; d++) {
        gemm_mfma_bf16<<<dim3(256, 6), 256, 0, stream>>>(
            XEMB, g1_wih + (size_t)d * 196608, g1_bih + d * 768,
            GI1B + (size_t)d * 32768 * 768, 32768, 768, 256);
    }
    // 3. GRU1 scan: 256 blocks (2 dirs x 128 streams) x 512 thr, reg-resident whh
    gru_scan_rreg<<<256, 512, 0, stream>>>(GI1B, GI1B + (size_t)32768 * 768, WPK1, g1_bhh, HBUF);

    float* QH = HBUF;
    float* AH = HBUF + (size_t)64 * 256 * 512;

    // 4. BiDAF1: c=QH, q=AH -> ATT (set)
    {
        float* CW = S1, *QW = S1 + 16384, *RM = S1 + 32768, *BBv = S1 + 49152, *Q2C = S1 + 65536;
        cwqw_kernel<<<32768, 64, 0, stream>>>(QH, AH, b1_w, CW, QW);
        smat_kernel<<<dim3(4, 4, 64), 256, 0, stream>>>(QH, AH, b1_w + 1024, b1_b, CW, QW, SMAT1);
        softmax_kernel<<<16384, 64, 0, stream>>>(SMAT1, RM);
        bb_kernel<<<64, 256, 0, stream>>>(RM, BBv);
        q2c_kernel<<<64, 256, 0, stream>>>(BBv, QH, Q2C);
        fixup03<<<16384, 256, 0, stream>>>(QH, Q2C, ATT, 0);
        c2q_fixup<<<dim3(4, 8, 64), 256, 0, stream>>>(SMAT1, AH, QH, ATT, 0);
    }

    // pack whh2 (HBUF dead, region free)
    pack_whh_bf<<<1536, 256, 0, stream>>>(g2_whh, WPK2);

    // 5. GRU2 input gates via MFMA: per dir, M=16384 N=768 K=2048
    for (int d = 0; d < 2; d++) {
        gemm_mfma_bf16<<<dim3(128, 6), 256, 0, stream>>>(
            ATT, g2_wih + (size_t)d * 1572864, g2_bih + d * 768,
            GI2B + (size_t)d * 16384 * 768, 16384, 768, 2048);
    }
    // 6. GRU2 scan: 128 blocks (2 dirs x 64 streams)
    gru_scan_rreg<<<128, 512, 0, stream>>>(GI2B, GI2B + (size_t)16384 * 768, WPK2, g2_bhh, AX2);

    // 7. BiDAF2: c=q=AX2 -> ATT (accumulate)
    {
        float* CW = S2, *QW = S2 + 16384, *RM = S2 + 32768, *BBv = S2 + 49152, *Q2C = S2 + 65536;
        cwqw_kernel<<<32768, 64, 0, stream>>>(AX2, AX2, b2_w, CW, QW);
        smat_kernel<<<dim3(4, 4, 64), 256, 0, stream>>>(AX2, AX2, b2_w + 1024, b2_b, CW, QW, SMAT2);
        softmax_kernel<<<16384, 64, 0, stream>>>(SMAT2, RM);
        bb_kernel<<<64, 256, 0, stream>>>(RM, BBv);
        q2c_kernel<<<64, 256, 0, stream>>>(BBv, AX2, Q2C);
        fixup03<<<16384, 256, 0, stream>>>(AX2, Q2C, ATT, 1);
        c2q_fixup<<<dim3(4, 8, 64), 256, 0, stream>>>(SMAT2, AX2, AX2, ATT, 1);
    }

    // 8. rank reduce
    float* PART = S2 + 98304;
    reduce1_kernel<<<dim3(32, 8), 256, 0, stream>>>(ATT, rank_w, PART);
    reduce2_kernel<<<1, 32, 0, stream>>>(PART, rank_b, out);
}